// Round 12
// baseline (66.060 us; speedup 1.0000x reference)
//
#include <hip/hip_runtime.h>

// ---------------- types / helpers ----------------
using f32x4  = __attribute__((ext_vector_type(4))) float;
using f32x2  = __attribute__((ext_vector_type(2))) float;
using bf16x8 = __attribute__((ext_vector_type(8))) short;

struct __attribute__((packed, aligned(4))) f4a { float x, y, z, w; };  // 4B-aligned float4

__device__ __forceinline__ unsigned short f2bf(float x) {
  unsigned u = __float_as_uint(x);
  u += 0x7FFFu + ((u >> 16) & 1u);   // round-to-nearest-even
  return (unsigned short)(u >> 16);
}
__device__ __forceinline__ float bflo(unsigned u) { return __uint_as_float(u << 16); }
__device__ __forceinline__ float bfhi(unsigned u) { return __uint_as_float(u & 0xffff0000u); }

// pc1: (8,1024,259)  pc2: (8,4096,131)  W1:(384,256) b1:(256) W2:(256,256) b2:(256)
// out: h (8*4096*256 fp32) then xyz2 (8*4096*3 fp32)
#define OUT_H_ELEMS 8388608

// u64 key = (f32 bits of d << 32) | idx ; d >= 0 so unsigned order == (d, idx) lex order.
__device__ __forceinline__ unsigned long long dkey(float d, int i) {
  return ((unsigned long long)__float_as_uint(d) << 32) | (unsigned)i;
}
#define KINSERT(K0, K1, K2, kk) { \
  bool L2 = (kk) < K2, L1 = (kk) < K1, L0 = (kk) < K0; \
  K2 = L1 ? K1 : (L2 ? (kk) : K2); \
  K1 = L0 ? K0 : (L1 ? (kk) : K1); \
  K0 = L0 ? (kk) : K0; }

#define CHAIN_UPD(dd, D0, D1, D2, I0, I1, I2, c) { \
  bool l2 = (dd) < D2, l1 = (dd) < D1, l0 = (dd) < D0; \
  D2 = l1 ? D1 : (l2 ? (dd) : D2);  I2 = l1 ? I1 : (l2 ? (c) : I2); \
  D1 = l0 ? D0 : (l1 ? (dd) : D1);  I1 = l0 ? I0 : (l1 ? (c) : I1); \
  D0 = l0 ? (dd) : D0;              I0 = l0 ? (c) : I0; }

// ---------------- prep: P1 bf16 table + weight transposes + xyz1 SoA (unchanged) ----------------
__global__ void prep(const float* __restrict__ pc1,
                     const float* __restrict__ W1, const float* __restrict__ W2,
                     unsigned short* __restrict__ W1t, unsigned short* __restrict__ W2t,
                     float* __restrict__ soa, unsigned short* __restrict__ P1) {
  int tid = blockIdx.x * 256 + threadIdx.x;
  if (tid < 524288) {
    int r = tid >> 6, l = tid & 63;
    const float* src = pc1 + (size_t)r * 259 + 3 + l * 4;
    ushort4 v;
    v.x = f2bf(src[0]); v.y = f2bf(src[1]); v.z = f2bf(src[2]); v.w = f2bf(src[3]);
    *(ushort4*)(P1 + ((size_t)r << 8) + l * 4) = v;
  } else if (tid < 622592) {
    int id = tid - 524288;                     // W1t[n][k] = W1[k][n], 256x384
    int n = id / 384, k = id - n * 384;
    W1t[id] = f2bf(W1[k * 256 + n]);
  } else if (tid < 688128) {
    int id2 = tid - 622592;                    // W2t[n][k] = W2[k][n], 256x256
    int n = id2 >> 8, k = id2 & 255;
    W2t[id2] = f2bf(W2[k * 256 + n]);
  } else if (tid < 712704) {
    int id = tid - 688128;                     // soa[b][coord][r] = xyz1
    int b = id / 3072, rem = id - b * 3072;
    int coord = rem >> 10, r = rem & 1023;
    soa[id] = pc1[(size_t)b * (1024 * 259) + (size_t)r * 259 + coord];
  }
}

// ---------------- front: 3-NN + inline interp, 2 queries per thread ----------------
// 1024 blocks x 256 threads; 32 queries/block; 16 lanes/query; each thread owns 2
// queries (q0,q0+1) sharing its LDS point reads (halves LDS demand per query,
// doubles independent math per read). Per-query partition identical to verified
// version (m = it*16+sub) -> bit-identical selection.
__global__ __launch_bounds__(256, 4) void front(
    const float* __restrict__ pc2, const float* __restrict__ soa,
    const unsigned short* __restrict__ P1,
    unsigned short* __restrict__ A1, float* __restrict__ xyzo) {
#pragma clang fp contract(off)
  __shared__ __align__(16) float s3[3][1024];
  const int t = threadIdx.x;
  const int blk = (blockIdx.x & 7) * 128 + (blockIdx.x >> 3);   // bijective (1024 = 8*128)
  const int b = blk >> 7;
  const int grp = blk & 127;

  // --- stage SoA xyz1 into LDS: 3 coalesced f32x4 per thread ---
  const f32x4* gsoa = (const f32x4*)(soa + b * 3072);
  f32x4* ls = (f32x4*)&s3[0][0];
  #pragma unroll
  for (int j = 0; j < 3; ++j) ls[j * 256 + t] = gsoa[j * 256 + t];
  __syncthreads();

  const int sub = t & 15;
  const int qpi = t >> 4;                      // 0..15
  const int q0 = grp * 32 + qpi * 2;
  const size_t qrow0 = (size_t)b * 4096 + q0;
  const size_t qrow1 = qrow0 + 1;
  const float* qpa = pc2 + qrow0 * 131;
  const float* qpb = pc2 + qrow1 * 131;
  const float qxa = qpa[0], qya = qpa[1], qza = qpa[2];
  const float qxb = qpb[0], qyb = qpb[1], qzb = qpb[2];
  const f32x2 qxa2 = {qxa, qxa}, qya2 = {qya, qya}, qza2 = {qza, qza};
  const f32x2 qxb2 = {qxb, qxb}, qyb2 = {qyb, qyb}, qzb2 = {qzb, qzb};

  // 4 chains per query (one per quad element)
  float dA0 = 3.4e38f, dA1 = 3.4e38f, dA2 = 3.4e38f;  int iA0 = -1, iA1 = -1, iA2 = -1;
  float dB0 = 3.4e38f, dB1 = 3.4e38f, dB2 = 3.4e38f;  int iB0 = -1, iB1 = -1, iB2 = -1;
  float dC0 = 3.4e38f, dC1 = 3.4e38f, dC2 = 3.4e38f;  int iC0 = -1, iC1 = -1, iC2 = -1;
  float dD0 = 3.4e38f, dD1 = 3.4e38f, dD2 = 3.4e38f;  int iD0 = -1, iD1 = -1, iD2 = -1;
  float dE0 = 3.4e38f, dE1 = 3.4e38f, dE2 = 3.4e38f;  int iE0 = -1, iE1 = -1, iE2 = -1;
  float dF0 = 3.4e38f, dF1 = 3.4e38f, dF2 = 3.4e38f;  int iF0 = -1, iF1 = -1, iF2 = -1;
  float dG0 = 3.4e38f, dG1 = 3.4e38f, dG2 = 3.4e38f;  int iG0 = -1, iG1 = -1, iG2 = -1;
  float dH0 = 3.4e38f, dH1 = 3.4e38f, dH2 = 3.4e38f;  int iH0 = -1, iH1 = -1, iH2 = -1;

  const f32x4* sXf = (const f32x4*)&s3[0][0];
  const f32x4* sYf = (const f32x4*)&s3[1][0];
  const f32x4* sZf = (const f32x4*)&s3[2][0];

  #pragma unroll 4
  for (int it = 0; it < 16; ++it) {
    const int m = it * 16 + sub;       // quad index 0..255 (same partition per query)
    f32x4 xv = sXf[m], yv = sYf[m], zv = sZf[m];
    f32x2 xlo = {xv[0], xv[1]}, xhi = {xv[2], xv[3]};
    f32x2 ylo = {yv[0], yv[1]}, yhi = {yv[2], yv[3]};
    f32x2 zlo = {zv[0], zv[1]}, zhi = {zv[2], zv[3]};
    // query 0: exact numpy order (dx*dx + dy*dy) + dz*dz, contract(off)
    f32x2 dxl = qxa2 - xlo, dyl = qya2 - ylo, dzl = qza2 - zlo;
    f32x2 dxh = qxa2 - xhi, dyh = qya2 - yhi, dzh = qza2 - zhi;
    f32x2 dla = (dxl * dxl + dyl * dyl) + dzl * dzl;
    f32x2 dha = (dxh * dxh + dyh * dyh) + dzh * dzh;
    // query 1
    f32x2 exl = qxb2 - xlo, eyl = qyb2 - ylo, ezl = qzb2 - zlo;
    f32x2 exh = qxb2 - xhi, eyh = qyb2 - yhi, ezh = qzb2 - zhi;
    f32x2 dlb = (exl * exl + eyl * eyl) + ezl * ezl;
    f32x2 dhb = (exh * exh + eyh * eyh) + ezh * ezh;
    const int c0 = m * 4;
    CHAIN_UPD(dla[0], dA0, dA1, dA2, iA0, iA1, iA2, c0)
    CHAIN_UPD(dla[1], dB0, dB1, dB2, iB0, iB1, iB2, c0 + 1)
    CHAIN_UPD(dha[0], dC0, dC1, dC2, iC0, iC1, iC2, c0 + 2)
    CHAIN_UPD(dha[1], dD0, dD1, dD2, iD0, iD1, iD2, c0 + 3)
    CHAIN_UPD(dlb[0], dE0, dE1, dE2, iE0, iE1, iE2, c0)
    CHAIN_UPD(dlb[1], dF0, dF1, dF2, iF0, iF1, iF2, c0 + 1)
    CHAIN_UPD(dhb[0], dG0, dG1, dG2, iG0, iG1, iG2, c0 + 2)
    CHAIN_UPD(dhb[1], dH0, dH1, dH2, iH0, iH1, iH2, c0 + 3)
  }

  // ---- query 0: merge chains + 16-lane shuffle merge (u64 exact lex) ----
  unsigned long long a0 = dkey(dA0, iA0), a1 = dkey(dA1, iA1), a2 = dkey(dA2, iA2);
  { unsigned long long kk;
    kk = dkey(dB0, iB0); KINSERT(a0, a1, a2, kk)  kk = dkey(dB1, iB1); KINSERT(a0, a1, a2, kk)
    kk = dkey(dB2, iB2); KINSERT(a0, a1, a2, kk)  kk = dkey(dC0, iC0); KINSERT(a0, a1, a2, kk)
    kk = dkey(dC1, iC1); KINSERT(a0, a1, a2, kk)  kk = dkey(dC2, iC2); KINSERT(a0, a1, a2, kk)
    kk = dkey(dD0, iD0); KINSERT(a0, a1, a2, kk)  kk = dkey(dD1, iD1); KINSERT(a0, a1, a2, kk)
    kk = dkey(dD2, iD2); KINSERT(a0, a1, a2, kk)
  }
  // ---- query 1 ----
  unsigned long long e0 = dkey(dE0, iE0), e1 = dkey(dE1, iE1), e2 = dkey(dE2, iE2);
  { unsigned long long kk;
    kk = dkey(dF0, iF0); KINSERT(e0, e1, e2, kk)  kk = dkey(dF1, iF1); KINSERT(e0, e1, e2, kk)
    kk = dkey(dF2, iF2); KINSERT(e0, e1, e2, kk)  kk = dkey(dG0, iG0); KINSERT(e0, e1, e2, kk)
    kk = dkey(dG1, iG1); KINSERT(e0, e1, e2, kk)  kk = dkey(dG2, iG2); KINSERT(e0, e1, e2, kk)
    kk = dkey(dH0, iH0); KINSERT(e0, e1, e2, kk)  kk = dkey(dH1, iH1); KINSERT(e0, e1, e2, kk)
    kk = dkey(dH2, iH2); KINSERT(e0, e1, e2, kk)
  }
  #pragma unroll
  for (int stp = 1; stp <= 8; stp <<= 1) {
    unsigned long long s0 = __shfl_xor(a0, stp, 64);
    unsigned long long s1 = __shfl_xor(a1, stp, 64);
    unsigned long long s2 = __shfl_xor(a2, stp, 64);
    KINSERT(a0, a1, a2, s0) KINSERT(a0, a1, a2, s1) KINSERT(a0, a1, a2, s2)
    unsigned long long u0 = __shfl_xor(e0, stp, 64);
    unsigned long long u1 = __shfl_xor(e1, stp, 64);
    unsigned long long u2 = __shfl_xor(e2, stp, 64);
    KINSERT(e0, e1, e2, u0) KINSERT(e0, e1, e2, u1) KINSERT(e0, e1, e2, u2)
  }

  // ---- weights (exact reference order) ----
  float d0a = __uint_as_float((unsigned)(a0 >> 32));
  float d1a = __uint_as_float((unsigned)(a1 >> 32));
  float d2a = __uint_as_float((unsigned)(a2 >> 32));
  const int i0a = (int)(a0 & 0xffffffffu), i1a = (int)(a1 & 0xffffffffu), i2a = (int)(a2 & 0xffffffffu);
  float t0a = fmaxf(d0a, 1e-7f), t1a = fmaxf(d1a, 1e-7f), t2a = fmaxf(d2a, 1e-7f);
  float r0a = 1.0f / t0a, r1a = 1.0f / t1a, r2a = 1.0f / t2a;
  float nra = (r0a + r1a) + r2a;
  float w0a = r0a / nra, w1a = r1a / nra, w2a = r2a / nra;

  float d0b = __uint_as_float((unsigned)(e0 >> 32));
  float d1b = __uint_as_float((unsigned)(e1 >> 32));
  float d2b = __uint_as_float((unsigned)(e2 >> 32));
  const int i0b = (int)(e0 & 0xffffffffu), i1b = (int)(e1 & 0xffffffffu), i2b = (int)(e2 & 0xffffffffu);
  float t0b = fmaxf(d0b, 1e-7f), t1b = fmaxf(d1b, 1e-7f), t2b = fmaxf(d2b, 1e-7f);
  float r0b = 1.0f / t0b, r1b = 1.0f / t1b, r2b = 1.0f / t2b;
  float nrb = (r0b + r1b) + r2b;
  float w0b = r0b / nrb, w1b = r1b / nrb, w2b = r2b / nrb;

  if (sub == 1) {
    xyzo[qrow0 * 3 + 0] = qxa; xyzo[qrow0 * 3 + 1] = qya; xyzo[qrow0 * 3 + 2] = qza;
  } else if (sub == 2) {
    xyzo[qrow1 * 3 + 0] = qxb; xyzo[qrow1 * 3 + 1] = qyb; xyzo[qrow1 * 3 + 2] = qzb;
  }

  // ---- inline interp from P1 bf16: lane covers cols [sub*16, +16) for both queries ----
  const unsigned short* P1b = P1 + ((size_t)b << 18);
  {
    const uint4* g0 = (const uint4*)(P1b + (i0a << 8) + sub * 16);
    const uint4* g1 = (const uint4*)(P1b + (i1a << 8) + sub * 16);
    const uint4* g2 = (const uint4*)(P1b + (i2a << 8) + sub * 16);
    unsigned short* arow = A1 + qrow0 * 384 + sub * 16;
    #pragma unroll
    for (int h = 0; h < 2; ++h) {
      uint4 u0 = g0[h], u1 = g1[h], u2 = g2[h];
      unsigned ov[4];
      const unsigned* p0 = (const unsigned*)&u0;
      const unsigned* p1 = (const unsigned*)&u1;
      const unsigned* p2 = (const unsigned*)&u2;
      #pragma unroll
      for (int c = 0; c < 4; ++c) {
        float lo = fmaf(w2a, bflo(p2[c]), fmaf(w1a, bflo(p1[c]), w0a * bflo(p0[c])));
        float hi = fmaf(w2a, bfhi(p2[c]), fmaf(w1a, bfhi(p1[c]), w0a * bfhi(p0[c])));
        ov[c] = (unsigned)f2bf(lo) | ((unsigned)f2bf(hi) << 16);
      }
      *(uint4*)(arow + h * 8) = *(const uint4*)ov;
    }
  }
  {
    const uint4* g0 = (const uint4*)(P1b + (i0b << 8) + sub * 16);
    const uint4* g1 = (const uint4*)(P1b + (i1b << 8) + sub * 16);
    const uint4* g2 = (const uint4*)(P1b + (i2b << 8) + sub * 16);
    unsigned short* arow = A1 + qrow1 * 384 + sub * 16;
    #pragma unroll
    for (int h = 0; h < 2; ++h) {
      uint4 u0 = g0[h], u1 = g1[h], u2 = g2[h];
      unsigned ov[4];
      const unsigned* p0 = (const unsigned*)&u0;
      const unsigned* p1 = (const unsigned*)&u1;
      const unsigned* p2 = (const unsigned*)&u2;
      #pragma unroll
      for (int c = 0; c < 4; ++c) {
        float lo = fmaf(w2b, bflo(p2[c]), fmaf(w1b, bflo(p1[c]), w0b * bflo(p0[c])));
        float hi = fmaf(w2b, bfhi(p2[c]), fmaf(w1b, bfhi(p1[c]), w0b * bfhi(p0[c])));
        ov[c] = (unsigned)f2bf(lo) | ((unsigned)f2bf(hi) << 16);
      }
      *(uint4*)(arow + h * 8) = *(const uint4*)ov;
    }
  }
  // ---- pc2 feature cols: lane covers A1 cols [256+sub*8, +8) for both queries ----
  {
    const float* gp = qpa + 3 + sub * 8;
    unsigned short* arow2 = A1 + qrow0 * 384 + 256 + sub * 8;
    #pragma unroll
    for (int c4 = 0; c4 < 2; ++c4) {
      f4a v = *(const f4a*)(gp + c4 * 4);
      ushort4 ov;
      ov.x = f2bf(v.x); ov.y = f2bf(v.y); ov.z = f2bf(v.z); ov.w = f2bf(v.w);
      *(ushort4*)(arow2 + c4 * 4) = ov;
    }
  }
  {
    const float* gp = qpb + 3 + sub * 8;
    unsigned short* arow2 = A1 + qrow1 * 384 + 256 + sub * 8;
    #pragma unroll
    for (int c4 = 0; c4 < 2; ++c4) {
      f4a v = *(const f4a*)(gp + c4 * 4);
      ushort4 ov;
      ov.x = f2bf(v.x); ov.y = f2bf(v.y); ov.z = f2bf(v.z); ov.w = f2bf(v.w);
      *(ushort4*)(arow2 + c4 * 4) = ov;
    }
  }
}

// ---------------- fused two-layer MFMA GEMM (160KB version, best measured; unchanged) ----------------
__global__ __launch_bounds__(512, 2) void fused_gemm(
    const unsigned short* __restrict__ A1, const unsigned short* __restrict__ W1t,
    const unsigned short* __restrict__ W2t, const float* __restrict__ b1,
    const float* __restrict__ b2, float* __restrict__ out) {
  extern __shared__ char lds[];
  char* Hbuf = lds;                       // [0, 64K): H tile 128x256 bf16, row stride 512B
  char* Bb[2] = { lds + 65536, lds + 98304 };
  char* Ab[2] = { lds + 131072, lds + 147456 };

  const int t = threadIdx.x, lane = t & 63, wv = t >> 6;
  const int wm = wv >> 2, wn = wv & 3;
  const int m0 = blockIdx.x * 128;

  const int arow = t >> 2, as0 = (t & 3) * 2;
  const int brow = t >> 1, bs0 = (t & 1) * 4;
  const unsigned short* gA  = A1  + (size_t)(m0 + arow) * 384 + as0 * 8;
  const unsigned short* gB1 = W1t + (size_t)brow * 384 + bs0 * 8;
  const unsigned short* gW2 = W2t + (size_t)brow * 256 + bs0 * 8;
  int awo[2], bwo[4];
  #pragma unroll
  for (int j = 0; j < 2; ++j)
    awo[j] = arow * 128 + (((as0 + j) * 16) ^ ((arow & 7) << 4));
  #pragma unroll
  for (int j = 0; j < 4; ++j)
    bwo[j] = brow * 128 + (((bs0 + j) * 16) ^ ((brow & 7) << 4));

  f32x4 zero = {0.f, 0.f, 0.f, 0.f};
  f32x4 acc[4][4];
  #pragma unroll
  for (int i = 0; i < 4; ++i)
    #pragma unroll
    for (int j = 0; j < 4; ++j) acc[i][j] = zero;

  f32x4 ra[2], rb[4];
  #pragma unroll
  for (int j = 0; j < 2; ++j) ra[j] = *(const f32x4*)(const void*)(gA + j * 8);
  #pragma unroll
  for (int j = 0; j < 4; ++j) rb[j] = *(const f32x4*)(const void*)(gB1 + j * 8);
  #pragma unroll
  for (int j = 0; j < 2; ++j) *(f32x4*)(void*)(Ab[0] + awo[j]) = ra[j];
  #pragma unroll
  for (int j = 0; j < 4; ++j) *(f32x4*)(void*)(Bb[0] + bwo[j]) = rb[j];
  __syncthreads();

  int cur = 0;
  #pragma unroll
  for (int kt = 0; kt < 6; ++kt) {
    if (kt < 5) {
      #pragma unroll
      for (int j = 0; j < 2; ++j) ra[j] = *(const f32x4*)(const void*)(gA + (kt + 1) * 64 + j * 8);
      #pragma unroll
      for (int j = 0; j < 4; ++j) rb[j] = *(const f32x4*)(const void*)(gB1 + (kt + 1) * 64 + j * 8);
    }
    #pragma unroll
    for (int ks = 0; ks < 2; ++ks) {
      bf16x8 af[4], bfr[4];
      const int sl = ks * 4 + (lane >> 4);
      #pragma unroll
      for (int i = 0; i < 4; ++i) {
        int ar = wm * 64 + i * 16 + (lane & 15);
        af[i] = *(const bf16x8*)(void*)(Ab[cur] + ar * 128 + ((sl * 16) ^ ((ar & 7) << 4)));
        int br = wn * 64 + i * 16 + (lane & 15);
        bfr[i] = *(const bf16x8*)(void*)(Bb[cur] + br * 128 + ((sl * 16) ^ ((br & 7) << 4)));
      }
      #pragma unroll
      for (int i = 0; i < 4; ++i)
        #pragma unroll
        for (int j = 0; j < 4; ++j)
          acc[i][j] = __builtin_amdgcn_mfma_f32_16x16x32_bf16(af[i], bfr[j], acc[i][j], 0, 0, 0);
    }
    if (kt < 5) {
      #pragma unroll
      for (int j = 0; j < 2; ++j) *(f32x4*)(void*)(Ab[cur ^ 1] + awo[j]) = ra[j];
      #pragma unroll
      for (int j = 0; j < 4; ++j) *(f32x4*)(void*)(Bb[cur ^ 1] + bwo[j]) = rb[j];
    }
    __syncthreads();
    cur ^= 1;
  }

  const int colb = wn * 64 + (lane & 15);
  const int rowb = wm * 64 + ((lane >> 4) << 2);
  #pragma unroll
  for (int ni = 0; ni < 4; ++ni) {
    float bv = b1[colb + ni * 16];
    #pragma unroll
    for (int mi = 0; mi < 4; ++mi) {
      #pragma unroll
      for (int r = 0; r < 4; ++r) {
        float v = fmaxf(acc[mi][ni][r] + bv, 0.0f);
        int row = rowb + mi * 16 + r, col = colb + ni * 16;
        *(unsigned short*)(Hbuf + row * 512 + ((col * 2) ^ ((row & 15) << 4))) = f2bf(v);
        acc[mi][ni][r] = 0.0f;
      }
    }
  }
  #pragma unroll
  for (int j = 0; j < 4; ++j) rb[j] = *(const f32x4*)(const void*)(gW2 + j * 8);
  #pragma unroll
  for (int j = 0; j < 4; ++j) *(f32x4*)(void*)(Bb[0] + bwo[j]) = rb[j];
  __syncthreads();

  cur = 0;
  #pragma unroll
  for (int kt = 0; kt < 4; ++kt) {
    if (kt < 3) {
      #pragma unroll
      for (int j = 0; j < 4; ++j) rb[j] = *(const f32x4*)(const void*)(gW2 + (kt + 1) * 64 + j * 8);
    }
    #pragma unroll
    for (int ks = 0; ks < 2; ++ks) {
      bf16x8 af[4], bfr[4];
      const int sl = ks * 4 + (lane >> 4);
      #pragma unroll
      for (int i = 0; i < 4; ++i) {
        int hr = wm * 64 + i * 16 + (lane & 15);
        af[i] = *(const bf16x8*)(void*)(Hbuf + hr * 512 + ((kt * 128 + sl * 16) ^ ((hr & 15) << 4)));
        int wr = wn * 64 + i * 16 + (lane & 15);
        bfr[i] = *(const bf16x8*)(void*)(Bb[cur] + wr * 128 + ((sl * 16) ^ ((wr & 7) << 4)));
      }
      #pragma unroll
      for (int i = 0; i < 4; ++i)
        #pragma unroll
        for (int j = 0; j < 4; ++j)
          acc[i][j] = __builtin_amdgcn_mfma_f32_16x16x32_bf16(af[i], bfr[j], acc[i][j], 0, 0, 0);
    }
    if (kt < 3) {
      #pragma unroll
      for (int j = 0; j < 4; ++j) *(f32x4*)(void*)(Bb[cur ^ 1] + bwo[j]) = rb[j];
    }
    __syncthreads();
    cur ^= 1;
  }

  #pragma unroll
  for (int ni = 0; ni < 4; ++ni) {
    float bv = b2[colb + ni * 16];
    #pragma unroll
    for (int mi = 0; mi < 4; ++mi) {
      #pragma unroll
      for (int r = 0; r < 4; ++r) {
        float v = fmaxf(acc[mi][ni][r] + bv, 0.0f);
        int row = rowb + mi * 16 + r, col = colb + ni * 16;
        *(float*)(lds + row * 1024 + ((col * 4) ^ ((row & 15) << 4))) = v;
      }
    }
  }
  __syncthreads();
  #pragma unroll
  for (int q = 0; q < 16; ++q) {
    int row = q * 8 + wv;
    f32x4 v = *(const f32x4*)(void*)(lds + row * 1024 + ((lane * 16) ^ ((row & 15) << 4)));
    *(f32x4*)(out + (size_t)(m0 + row) * 256 + lane * 4) = v;
  }
}

// ---------------- launch ----------------
extern "C" void kernel_launch(void* const* d_in, const int* in_sizes, int n_in,
                              void* d_out, int out_size, void* d_ws, size_t ws_size,
                              hipStream_t stream) {
  const float* pc1 = (const float*)d_in[0];
  const float* pc2 = (const float*)d_in[1];
  const float* W1  = (const float*)d_in[2];
  const float* b1  = (const float*)d_in[3];
  const float* W2  = (const float*)d_in[4];
  const float* b2  = (const float*)d_in[5];
  float* out = (float*)d_out;
  char* ws = (char*)d_ws;

  unsigned short* W1t = (unsigned short*)(ws + 0);        // 256x384 bf16
  unsigned short* W2t = (unsigned short*)(ws + 196608);   // 256x256 bf16
  float*          soa = (float*)(ws + 327680);            // 8x3x1024 f32
  unsigned short* P1  = (unsigned short*)(ws + 425984);   // 8x1024x256 bf16
  unsigned short* A1  = (unsigned short*)(ws + 4620288);  // 32768x384 bf16
  // ws usage ends at 29,786,112 bytes

  hipFuncSetAttribute((const void*)fused_gemm, hipFuncAttributeMaxDynamicSharedMemorySize, 163840);

  prep<<<2784, 256, 0, stream>>>(pc1, W1, W2, W1t, W2t, soa, P1);
  front<<<1024, 256, 0, stream>>>(pc2, soa, P1, A1, out + OUT_H_ELEMS);
  fused_gemm<<<256, 512, 163840, stream>>>(A1, W1t, W2t, b1, b2, out);
}

// Round 13
// 59.071 us; speedup vs baseline: 1.1183x; 1.1183x over previous
//
#include <hip/hip_runtime.h>

// ---------------- types / helpers ----------------
using f32x4  = __attribute__((ext_vector_type(4))) float;
using f32x2  = __attribute__((ext_vector_type(2))) float;
using bf16x8 = __attribute__((ext_vector_type(8))) short;

struct __attribute__((packed, aligned(4))) f4a { float x, y, z, w; };  // 4B-aligned float4

__device__ __forceinline__ unsigned short f2bf(float x) {
  unsigned u = __float_as_uint(x);
  u += 0x7FFFu + ((u >> 16) & 1u);   // round-to-nearest-even
  return (unsigned short)(u >> 16);
}

// pc1: (8,1024,259)  pc2: (8,4096,131)  W1:(384,256) b1:(256) W2:(256,256) b2:(256)
// out: h (8*4096*256 fp32) then xyz2 (8*4096*3 fp32)
#define OUT_H_ELEMS 8388608

// u64 key = (f32 bits of d << 32) | idx ; d >= 0 so unsigned order == (d, idx) lex order.
__device__ __forceinline__ unsigned long long dkey(float d, int i) {
  return ((unsigned long long)__float_as_uint(d) << 32) | (unsigned)i;
}
#define KINSERT(kk) { \
  bool L2 = (kk) < k2, L1 = (kk) < k1, L0 = (kk) < k0; \
  k2 = L1 ? k1 : (L2 ? (kk) : k2); \
  k1 = L0 ? k0 : (L1 ? (kk) : k1); \
  k0 = L0 ? (kk) : k0; }

#define CHAIN_UPD(dd, D0, D1, D2, I0, I1, I2, c) { \
  bool l2 = (dd) < D2, l1 = (dd) < D1, l0 = (dd) < D0; \
  D2 = l1 ? D1 : (l2 ? (dd) : D2);  I2 = l1 ? I1 : (l2 ? (c) : I2); \
  D1 = l0 ? D0 : (l1 ? (dd) : D1);  I1 = l0 ? I0 : (l1 ? (c) : I1); \
  D0 = l0 ? (dd) : D0;              I0 = l0 ? (c) : I0; }

// ---------------- miniprep: weight transposes only (off critical path) ----------------
__global__ void miniprep(const float* __restrict__ W1, const float* __restrict__ W2,
                         unsigned short* __restrict__ W1t, unsigned short* __restrict__ W2t) {
  int tid = blockIdx.x * 256 + threadIdx.x;
  if (tid < 98304) {                           // W1t[n][k] = W1[k][n], 256x384
    int n = tid / 384, k = tid - n * 384;
    W1t[tid] = f2bf(W1[k * 256 + n]);
  } else if (tid < 163840) {                   // W2t[n][k] = W2[k][n], 256x256
    int id2 = tid - 98304;
    int n = id2 >> 8, k = id2 & 255;
    W2t[id2] = f2bf(W2[k * 256 + n]);
  }
}

// ---------------- front: self-contained 3-NN + inline interp (direct from pc1) ----------------
// 2048 blocks x 256 threads; 16 queries/block, 16 lanes/query. Batch b == XCD b
// (bijective swizzle), so pc1 batch region (~1 MB) is L2-local for the gathers.
__global__ __launch_bounds__(256, 4) void front(
    const float* __restrict__ pc1, const float* __restrict__ pc2,
    unsigned short* __restrict__ A1, float* __restrict__ xyzo) {
#pragma clang fp contract(off)
  __shared__ __align__(16) float sX[1024];
  __shared__ __align__(16) float sY[1024];
  __shared__ __align__(16) float sZ[1024];
  const int t = threadIdx.x;
  const int blk = (blockIdx.x & 7) * 256 + (blockIdx.x >> 3);   // bijective (2048 = 8*256)
  const int b = blk >> 8;
  const int chunk = blk & 255;

  // --- stage xyz1 of this batch into SoA LDS (R5-verified) ---
  const float* p1b = pc1 + (size_t)b * (1024 * 259);
  #pragma unroll
  for (int j = 0; j < 4; ++j) {
    int r = t + j * 256;
    const float* p = p1b + (size_t)r * 259;
    sX[r] = p[0]; sY[r] = p[1]; sZ[r] = p[2];
  }
  __syncthreads();

  const int q = chunk * 16 + (t >> 4);
  const int sub = t & 15;
  const size_t qrow = (size_t)b * 4096 + q;
  const float* qp = pc2 + qrow * 131;
  const float qx = qp[0], qy = qp[1], qz = qp[2];
  const f32x2 qx2 = {qx, qx}, qy2 = {qy, qy}, qz2 = {qz, qz};

  // 4 independent top-3 chains, one per element of each float4 quad
  float dA0 = 3.4e38f, dA1 = 3.4e38f, dA2 = 3.4e38f;  int iA0 = -1, iA1 = -1, iA2 = -1;
  float dB0 = 3.4e38f, dB1 = 3.4e38f, dB2 = 3.4e38f;  int iB0 = -1, iB1 = -1, iB2 = -1;
  float dC0 = 3.4e38f, dC1 = 3.4e38f, dC2 = 3.4e38f;  int iC0 = -1, iC1 = -1, iC2 = -1;
  float dD0 = 3.4e38f, dD1 = 3.4e38f, dD2 = 3.4e38f;  int iD0 = -1, iD1 = -1, iD2 = -1;

  const f32x4* sXf = (const f32x4*)sX;
  const f32x4* sYf = (const f32x4*)sY;
  const f32x4* sZf = (const f32x4*)sZ;

  #pragma unroll 4
  for (int it = 0; it < 16; ++it) {
    const int m = it * 16 + sub;       // quad index 0..255
    f32x4 xv = sXf[m], yv = sYf[m], zv = sZf[m];
    // packed exact math, numpy order: (dx*dx + dy*dy) + dz*dz, contract(off)
    f32x2 xlo = {xv[0], xv[1]}, xhi = {xv[2], xv[3]};
    f32x2 ylo = {yv[0], yv[1]}, yhi = {yv[2], yv[3]};
    f32x2 zlo = {zv[0], zv[1]}, zhi = {zv[2], zv[3]};
    f32x2 dxl = qx2 - xlo, dyl = qy2 - ylo, dzl = qz2 - zlo;
    f32x2 dxh = qx2 - xhi, dyh = qy2 - yhi, dzh = qz2 - zhi;
    f32x2 dl = (dxl * dxl + dyl * dyl) + dzl * dzl;
    f32x2 dh = (dxh * dxh + dyh * dyh) + dzh * dzh;
    const int c0 = m * 4;
    CHAIN_UPD(dl[0], dA0, dA1, dA2, iA0, iA1, iA2, c0)
    CHAIN_UPD(dl[1], dB0, dB1, dB2, iB0, iB1, iB2, c0 + 1)
    CHAIN_UPD(dh[0], dC0, dC1, dC2, iC0, iC1, iC2, c0 + 2)
    CHAIN_UPD(dh[1], dD0, dD1, dD2, iD0, iD1, iD2, c0 + 3)
  }

  // ---- merges via u64 (d,idx) keys: exact lexicographic (R11-verified) ----
  unsigned long long k0 = dkey(dA0, iA0), k1 = dkey(dA1, iA1), k2 = dkey(dA2, iA2);
  { unsigned long long kk;
    kk = dkey(dB0, iB0); KINSERT(kk)  kk = dkey(dB1, iB1); KINSERT(kk)  kk = dkey(dB2, iB2); KINSERT(kk)
    kk = dkey(dC0, iC0); KINSERT(kk)  kk = dkey(dC1, iC1); KINSERT(kk)  kk = dkey(dC2, iC2); KINSERT(kk)
    kk = dkey(dD0, iD0); KINSERT(kk)  kk = dkey(dD1, iD1); KINSERT(kk)  kk = dkey(dD2, iD2); KINSERT(kk)
  }
  #pragma unroll
  for (int stp = 1; stp <= 8; stp <<= 1) {
    unsigned long long e0 = __shfl_xor(k0, stp, 64);
    unsigned long long e1 = __shfl_xor(k1, stp, 64);
    unsigned long long e2 = __shfl_xor(k2, stp, 64);
    KINSERT(e0) KINSERT(e1) KINSERT(e2)
  }
  float d0 = __uint_as_float((unsigned)(k0 >> 32));
  float d1 = __uint_as_float((unsigned)(k1 >> 32));
  float d2v = __uint_as_float((unsigned)(k2 >> 32));
  const int i0 = (int)(k0 & 0xffffffffu);
  const int i1 = (int)(k1 & 0xffffffffu);
  const int i2 = (int)(k2 & 0xffffffffu);

  // weights (exact reference order)
  float t0 = fmaxf(d0, 1e-7f), t1 = fmaxf(d1, 1e-7f), t2 = fmaxf(d2v, 1e-7f);
  float r0 = 1.0f / t0, r1 = 1.0f / t1, r2 = 1.0f / t2;
  float nrm = (r0 + r1) + r2;
  float w0v = r0 / nrm, w1v = r1 / nrm, w2v = r2 / nrm;

  if (sub == 1) {
    xyzo[qrow * 3 + 0] = qx; xyzo[qrow * 3 + 1] = qy; xyzo[qrow * 3 + 2] = qz;
  }

  // --- inline interpolation directly from pc1 f32 (R3-verified): cols [sub*16, +16) ---
  const float* g0p = p1b + (size_t)i0 * 259 + 3 + sub * 16;
  const float* g1p = p1b + (size_t)i1 * 259 + 3 + sub * 16;
  const float* g2p = p1b + (size_t)i2 * 259 + 3 + sub * 16;
  unsigned short* arow = A1 + qrow * 384 + sub * 16;
  #pragma unroll
  for (int c4 = 0; c4 < 4; ++c4) {
    f4a a0 = *(const f4a*)(g0p + c4 * 4);
    f4a a1 = *(const f4a*)(g1p + c4 * 4);
    f4a a2 = *(const f4a*)(g2p + c4 * 4);
    ushort4 ov;
    ov.x = f2bf(fmaf(w2v, a2.x, fmaf(w1v, a1.x, w0v * a0.x)));
    ov.y = f2bf(fmaf(w2v, a2.y, fmaf(w1v, a1.y, w0v * a0.y)));
    ov.z = f2bf(fmaf(w2v, a2.z, fmaf(w1v, a1.z, w0v * a0.z)));
    ov.w = f2bf(fmaf(w2v, a2.w, fmaf(w1v, a1.w, w0v * a0.w)));
    *(ushort4*)(arow + c4 * 4) = ov;
  }
  // --- pc2 feature cols: lane covers A1 cols [256+sub*8, +8) ---
  const float* gp = qp + 3 + sub * 8;
  unsigned short* arow2 = A1 + qrow * 384 + 256 + sub * 8;
  #pragma unroll
  for (int c4 = 0; c4 < 2; ++c4) {
    f4a v = *(const f4a*)(gp + c4 * 4);
    ushort4 ov;
    ov.x = f2bf(v.x); ov.y = f2bf(v.y); ov.z = f2bf(v.z); ov.w = f2bf(v.w);
    *(ushort4*)(arow2 + c4 * 4) = ov;
  }
}

// ---------------- fused two-layer MFMA GEMM (160KB version, best measured; unchanged) ----------------
__global__ __launch_bounds__(512, 2) void fused_gemm(
    const unsigned short* __restrict__ A1, const unsigned short* __restrict__ W1t,
    const unsigned short* __restrict__ W2t, const float* __restrict__ b1,
    const float* __restrict__ b2, float* __restrict__ out) {
  extern __shared__ char lds[];
  char* Hbuf = lds;                       // [0, 64K): H tile 128x256 bf16, row stride 512B
  char* Bb[2] = { lds + 65536, lds + 98304 };
  char* Ab[2] = { lds + 131072, lds + 147456 };

  const int t = threadIdx.x, lane = t & 63, wv = t >> 6;
  const int wm = wv >> 2, wn = wv & 3;
  const int m0 = blockIdx.x * 128;

  const int arow = t >> 2, as0 = (t & 3) * 2;
  const int brow = t >> 1, bs0 = (t & 1) * 4;
  const unsigned short* gA  = A1  + (size_t)(m0 + arow) * 384 + as0 * 8;
  const unsigned short* gB1 = W1t + (size_t)brow * 384 + bs0 * 8;
  const unsigned short* gW2 = W2t + (size_t)brow * 256 + bs0 * 8;
  int awo[2], bwo[4];
  #pragma unroll
  for (int j = 0; j < 2; ++j)
    awo[j] = arow * 128 + (((as0 + j) * 16) ^ ((arow & 7) << 4));
  #pragma unroll
  for (int j = 0; j < 4; ++j)
    bwo[j] = brow * 128 + (((bs0 + j) * 16) ^ ((brow & 7) << 4));

  f32x4 zero = {0.f, 0.f, 0.f, 0.f};
  f32x4 acc[4][4];
  #pragma unroll
  for (int i = 0; i < 4; ++i)
    #pragma unroll
    for (int j = 0; j < 4; ++j) acc[i][j] = zero;

  f32x4 ra[2], rb[4];
  #pragma unroll
  for (int j = 0; j < 2; ++j) ra[j] = *(const f32x4*)(const void*)(gA + j * 8);
  #pragma unroll
  for (int j = 0; j < 4; ++j) rb[j] = *(const f32x4*)(const void*)(gB1 + j * 8);
  #pragma unroll
  for (int j = 0; j < 2; ++j) *(f32x4*)(void*)(Ab[0] + awo[j]) = ra[j];
  #pragma unroll
  for (int j = 0; j < 4; ++j) *(f32x4*)(void*)(Bb[0] + bwo[j]) = rb[j];
  __syncthreads();

  int cur = 0;
  #pragma unroll
  for (int kt = 0; kt < 6; ++kt) {
    if (kt < 5) {
      #pragma unroll
      for (int j = 0; j < 2; ++j) ra[j] = *(const f32x4*)(const void*)(gA + (kt + 1) * 64 + j * 8);
      #pragma unroll
      for (int j = 0; j < 4; ++j) rb[j] = *(const f32x4*)(const void*)(gB1 + (kt + 1) * 64 + j * 8);
    }
    #pragma unroll
    for (int ks = 0; ks < 2; ++ks) {
      bf16x8 af[4], bfr[4];
      const int sl = ks * 4 + (lane >> 4);
      #pragma unroll
      for (int i = 0; i < 4; ++i) {
        int ar = wm * 64 + i * 16 + (lane & 15);
        af[i] = *(const bf16x8*)(void*)(Ab[cur] + ar * 128 + ((sl * 16) ^ ((ar & 7) << 4)));
        int br = wn * 64 + i * 16 + (lane & 15);
        bfr[i] = *(const bf16x8*)(void*)(Bb[cur] + br * 128 + ((sl * 16) ^ ((br & 7) << 4)));
      }
      #pragma unroll
      for (int i = 0; i < 4; ++i)
        #pragma unroll
        for (int j = 0; j < 4; ++j)
          acc[i][j] = __builtin_amdgcn_mfma_f32_16x16x32_bf16(af[i], bfr[j], acc[i][j], 0, 0, 0);
    }
    if (kt < 5) {
      #pragma unroll
      for (int j = 0; j < 2; ++j) *(f32x4*)(void*)(Ab[cur ^ 1] + awo[j]) = ra[j];
      #pragma unroll
      for (int j = 0; j < 4; ++j) *(f32x4*)(void*)(Bb[cur ^ 1] + bwo[j]) = rb[j];
    }
    __syncthreads();
    cur ^= 1;
  }

  const int colb = wn * 64 + (lane & 15);
  const int rowb = wm * 64 + ((lane >> 4) << 2);
  #pragma unroll
  for (int ni = 0; ni < 4; ++ni) {
    float bv = b1[colb + ni * 16];
    #pragma unroll
    for (int mi = 0; mi < 4; ++mi) {
      #pragma unroll
      for (int r = 0; r < 4; ++r) {
        float v = fmaxf(acc[mi][ni][r] + bv, 0.0f);
        int row = rowb + mi * 16 + r, col = colb + ni * 16;
        *(unsigned short*)(Hbuf + row * 512 + ((col * 2) ^ ((row & 15) << 4))) = f2bf(v);
        acc[mi][ni][r] = 0.0f;
      }
    }
  }
  #pragma unroll
  for (int j = 0; j < 4; ++j) rb[j] = *(const f32x4*)(const void*)(gW2 + j * 8);
  #pragma unroll
  for (int j = 0; j < 4; ++j) *(f32x4*)(void*)(Bb[0] + bwo[j]) = rb[j];
  __syncthreads();

  cur = 0;
  #pragma unroll
  for (int kt = 0; kt < 4; ++kt) {
    if (kt < 3) {
      #pragma unroll
      for (int j = 0; j < 4; ++j) rb[j] = *(const f32x4*)(const void*)(gW2 + (kt + 1) * 64 + j * 8);
    }
    #pragma unroll
    for (int ks = 0; ks < 2; ++ks) {
      bf16x8 af[4], bfr[4];
      const int sl = ks * 4 + (lane >> 4);
      #pragma unroll
      for (int i = 0; i < 4; ++i) {
        int hr = wm * 64 + i * 16 + (lane & 15);
        af[i] = *(const bf16x8*)(void*)(Hbuf + hr * 512 + ((kt * 128 + sl * 16) ^ ((hr & 15) << 4)));
        int wr = wn * 64 + i * 16 + (lane & 15);
        bfr[i] = *(const bf16x8*)(void*)(Bb[cur] + wr * 128 + ((sl * 16) ^ ((wr & 7) << 4)));
      }
      #pragma unroll
      for (int i = 0; i < 4; ++i)
        #pragma unroll
        for (int j = 0; j < 4; ++j)
          acc[i][j] = __builtin_amdgcn_mfma_f32_16x16x32_bf16(af[i], bfr[j], acc[i][j], 0, 0, 0);
    }
    if (kt < 3) {
      #pragma unroll
      for (int j = 0; j < 4; ++j) *(f32x4*)(void*)(Bb[cur ^ 1] + bwo[j]) = rb[j];
    }
    __syncthreads();
    cur ^= 1;
  }

  #pragma unroll
  for (int ni = 0; ni < 4; ++ni) {
    float bv = b2[colb + ni * 16];
    #pragma unroll
    for (int mi = 0; mi < 4; ++mi) {
      #pragma unroll
      for (int r = 0; r < 4; ++r) {
        float v = fmaxf(acc[mi][ni][r] + bv, 0.0f);
        int row = rowb + mi * 16 + r, col = colb + ni * 16;
        *(float*)(lds + row * 1024 + ((col * 4) ^ ((row & 15) << 4))) = v;
      }
    }
  }
  __syncthreads();
  #pragma unroll
  for (int q = 0; q < 16; ++q) {
    int row = q * 8 + wv;
    f32x4 v = *(const f32x4*)(void*)(lds + row * 1024 + ((lane * 16) ^ ((row & 15) << 4)));
    *(f32x4*)(out + (size_t)(m0 + row) * 256 + lane * 4) = v;
  }
}

// ---------------- launch ----------------
extern "C" void kernel_launch(void* const* d_in, const int* in_sizes, int n_in,
                              void* d_out, int out_size, void* d_ws, size_t ws_size,
                              hipStream_t stream) {
  const float* pc1 = (const float*)d_in[0];
  const float* pc2 = (const float*)d_in[1];
  const float* W1  = (const float*)d_in[2];
  const float* b1  = (const float*)d_in[3];
  const float* W2  = (const float*)d_in[4];
  const float* b2  = (const float*)d_in[5];
  float* out = (float*)d_out;
  char* ws = (char*)d_ws;

  unsigned short* W1t = (unsigned short*)(ws + 0);        // 256x384 bf16
  unsigned short* W2t = (unsigned short*)(ws + 196608);   // 256x256 bf16
  unsigned short* A1  = (unsigned short*)(ws + 327680);   // 32768x384 bf16
  // ws usage ends at 25,493,504 bytes

  hipFuncSetAttribute((const void*)fused_gemm, hipFuncAttributeMaxDynamicSharedMemorySize, 163840);

  front<<<2048, 256, 0, stream>>>(pc1, pc2, A1, out + OUT_H_ELEMS);   // independent, longest
  miniprep<<<640, 256, 0, stream>>>(W1, W2, W1t, W2t);                // hides in front's tail
  fused_gemm<<<256, 512, 163840, stream>>>(A1, W1t, W2t, b1, b2, out);
}